// Round 13
// baseline (369.602 us; speedup 1.0000x reference)
//
#include <hip/hip_runtime.h>
#include <cstdint>
#include <cstddef>

typedef unsigned long long u64;
typedef unsigned int u32;
typedef unsigned short u16;
typedef unsigned char u8;

#define R_ANCH 96000
#define NIMG   8
#define KMIX   5
#define PRE    2000
#define POST   1000
#define NGT    32
#define NCHUNK 375   // R_ANCH / 256
#define NBLK   48    // blocks per image for grid-stride scan kernels
#define MROW   2048  // maskLT row stride (padded PRE)
#define GC_STRIDE 16 // gcnt padding: 64 B per image (atomic-line isolation)
#define SCAP   16    // per-row suppressor-list capacity (overflow -> dense path)

#define IMG_SZ        1280.0f
#define NMS_T         0.7f
#define SCALE_CLAMP_F 4.135166556742356f
#define HALF_L2PI     0.9189385332046727f

__device__ __forceinline__ u64 make_key(float s, int r) {
  u32 u = __float_as_uint(s);
  u = (u & 0x80000000u) ? ~u : (u | 0x80000000u);
  return ((u64)u << 32) | (u64)(0xFFFFFFFFu - (u32)r);
}

__device__ __forceinline__ float dec_score(u64 key) {
  u32 o = (u32)(key >> 32);
  u32 bits = (o & 0x80000000u) ? (o ^ 0x80000000u) : ~o;
  return __uint_as_float(bits);
}

// EXACT-PATH IoU (NMS only): must match reference bit-for-bit since NMS
// decisions select whole boxes. Label-path kernels (kA/kL1/kL2) use
// division-free cross-multiplied compares instead (loss-only, tol 25.6).
__device__ __forceinline__ float iou_pair(float a0,float a1,float a2,float a3,
                                          float b0,float b1,float b2,float b3) {
#pragma clang fp contract(off)
  float areaA = (a2-a0)*(a3-a1);
  float areaB = (b2-b0)*(b3-b1);
  float lx=fmaxf(a0,b0), ly=fmaxf(a1,b1);
  float rx=fminf(a2,b2), ry=fminf(a3,b3);
  float iw=fmaxf(rx-lx,0.0f), ih=fmaxf(ry-ly,0.0f);
  float inter=iw*ih;
  return inter / fmaxf(areaA+areaB-inter, 1e-9f);
}

// pick: from a 2048-bin histogram (bin d high = higher keys), find the bin
// containing the k-th largest key. 256 threads. s_i >= 8 ints, s_u >= 3 u32.
__device__ __forceinline__ void pick2048(const u32* __restrict__ hist, int k,
                                         int* s_i, u32* s_u,
                                         int& d_out, int& k_out, u32& cnt_out) {
  int tid = threadIdx.x;
  int lane = tid & 63, w = tid >> 6;
  u32 h[8]; u32 ssum = 0;
#pragma unroll
  for (int i=0;i<8;++i){ h[i] = hist[2047 - (tid*8 + i)]; ssum += h[i]; }
  u32 incl = ssum;
  for (int off=1; off<64; off<<=1){
    u32 t = (u32)__shfl_up((int)incl, off, 64);
    if (lane >= off) incl += t;
  }
  if (lane==63) s_i[w] = (int)incl;
  __syncthreads();
  u32 base = 0;
  for (int ww=0; ww<w; ++ww) base += (u32)s_i[ww];
  u32 run = base + incl - ssum;              // exclusive prefix (descending keys)
#pragma unroll
  for (int i=0;i<8;++i){
    u32 nr = run + h[i];
    if (run < (u32)k && nr >= (u32)k){       // unique crossing thread
      s_u[0] = (u32)(2047 - (tid*8+i));
      s_u[1] = (u32)k - run;
      s_u[2] = h[i];
    }
    run = nr;
  }
  __syncthreads();
  d_out = (int)s_u[0]; k_out = (int)s_u[1]; cnt_out = s_u[2];
  __syncthreads();
}

// ---------------- zero: contiguous workspace region -----------------------
__global__ void kZero(u32* z, int nwords) {
  for (int i = blockIdx.x*256 + threadIdx.x; i < nwords; i += gridDim.x*256)
    z[i] = 0u;
}

// ---------------- A: MDN moments + hist0 + per-anchor NLL/loc -------------
__global__ __launch_bounds__(256) void kA_mdn(
    const float* __restrict__ pi, const float* __restrict__ mu,
    const float* __restrict__ sigma, float* __restrict__ logits,
    float* __restrict__ epis, float* __restrict__ alea,
    u32* __restrict__ hist0,
    const float* __restrict__ anchors, const float* __restrict__ gt,
    const float* __restrict__ deltas,
    float* __restrict__ nll_o, float* __restrict__ loc_o) {
  __shared__ u32 s_h[2048];
  __shared__ float s_gt[NGT*4];
  int tid = threadIdx.x;
  int r = blockIdx.x*256 + tid;
  int img = blockIdx.y;
  for (int b=tid; b<2048; b+=256) s_h[b]=0u;
  if (tid < NGT*4) s_gt[tid] = gt[img*NGT*4 + tid];
  size_t base = (size_t)img*KMIX*R_ANCH + r;
  float p[KMIX], m[KMIX], s[KMIX];
#pragma unroll
  for (int k=0;k<KMIX;k++){
    p[k]=pi[base+(size_t)k*R_ANCH];
    m[k]=mu[base+(size_t)k*R_ANCH];
    s[k]=sigma[base+(size_t)k*R_ANCH];
  }
  float mx = p[0];
#pragma unroll
  for (int k=1;k<KMIX;k++) mx = fmaxf(mx,p[k]);
  float e[KMIX]; float sum = 0.0f;
#pragma unroll
  for (int k=0;k<KMIX;k++){ e[k]=expf(p[k]-mx); sum += e[k]; }
  float w[KMIX]; float lg = 0.0f;
#pragma unroll
  for (int k=0;k<KMIX;k++){ w[k]=e[k]/sum; lg += w[k]*m[k]; }
  float ep = 0.0f, al = 0.0f;
#pragma unroll
  for (int k=0;k<KMIX;k++){ float d=m[k]-lg; ep += w[k]*d*d; al += w[k]*s[k]*s[k]; }
  size_t o = (size_t)img*R_ANCH + r;
  logits[o]=lg; epis[o]=ep; alea[o]=al;
  __syncthreads();                           // s_h zero + s_gt complete
  u64 key = make_key(lg, r);
  atomicAdd(&s_h[(u32)(key>>53)], 1u);
  // per-anchor best IoU via cross-mult argmax (division-free)
  float4 a = ((const float4*)anchors)[r];
  float aA = (a.z-a.x)*(a.w-a.y);
  float bi = -1.0f, bu = 1.0f; int idx = 0;
#pragma unroll 4
  for (int g=0; g<NGT; ++g){
    float g0=s_gt[g*4], g1=s_gt[g*4+1], g2=s_gt[g*4+2], g3=s_gt[g*4+3];
    float ga=(g2-g0)*(g3-g1);
    float lx=fmaxf(g0,a.x), ly=fmaxf(g1,a.y);
    float rx=fminf(g2,a.z), ry=fminf(g3,a.w);
    float iw=fmaxf(rx-lx,0.0f), ih=fmaxf(ry-ly,0.0f);
    float inter=iw*ih;
    float uni = fmaxf(ga + aA - inter, 1e-9f);
    if (inter*bu > bi*uni){ bi=inter; bu=uni; idx=g; }
  }
  float vbest = bi/bu;
  // NLL (identical arithmetic to reference path)
  float lsum = logf(sum);
  float t_ = fminf(fmaxf(vbest, 0.0f), 1.0f);
  float comp[KMIX];
#pragma unroll
  for (int k=0;k<KMIX;k++){
    float z = (t_ - m[k]) / s[k];
    comp[k] = (p[k]-mx-lsum) - 0.5f*z*z - logf(s[k]) - HALF_L2PI;
  }
  float cm = comp[0];
#pragma unroll
  for (int k=1;k<KMIX;k++) cm = fmaxf(cm, comp[k]);
  float se = 0.0f;
#pragma unroll
  for (int k=0;k<KMIX;k++) se += expf(comp[k]-cm);
  float nll = -(cm + logf(se));
  // loc L1 vs matched gt
  const float* gb = &s_gt[idx*4];
  float sw = a.z-a.x, sh = a.w-a.y;
  float scx = a.x+0.5f*sw, scy = a.y+0.5f*sh;
  float tw = gb[2]-gb[0], th = gb[3]-gb[1];
  float tcx = gb[0]+0.5f*tw, tcy = gb[1]+0.5f*th;
  float4 d = ((const float4*)deltas)[(size_t)img*R_ANCH + r];
  float loc = fabsf(d.x-(tcx-scx)/sw) + fabsf(d.y-(tcy-scy)/sh)
            + fabsf(d.z-logf(tw/sw)) + fabsf(d.w-logf(th/sh));
  nll_o[o] = nll; loc_o[o] = loc;
  __syncthreads();
  for (int b=tid; b<2048; b+=256){ u32 v=s_h[b]; if(v) atomicAdd(&hist0[img*2048+b], v); }
}

// ---------------- L1: best IoU per GT — cross-mult, 1 div per (thread,g) --
__global__ __launch_bounds__(256) void kL1_bestgt(const float* __restrict__ anchors,
                                                  const float* __restrict__ gt,
                                                  int* __restrict__ best) {
  __shared__ float s_gt[NGT*4];
  __shared__ float s_ga[NGT];
  __shared__ int s_best[NGT];
  int tid = threadIdx.x, img = blockIdx.y;
  if (tid < NGT*4) s_gt[tid] = gt[img*NGT*4 + tid];
  if (tid < NGT){
    const float* g4 = gt + img*NGT*4 + tid*4;
    s_ga[tid] = (g4[2]-g4[0])*(g4[3]-g4[1]);
    s_best[tid] = 0;
  }
  __syncthreads();
  float4 an[8]; float aA[8];
#pragma unroll
  for (int q=0; q<8; ++q){
    int r = blockIdx.x*256 + tid + q*(NBLK*256);
    an[q] = (r < R_ANCH) ? ((const float4*)anchors)[r]
                         : make_float4(0.f,0.f,0.f,0.f);   // IoU=0, inert
    aA[q] = (an[q].z-an[q].x)*(an[q].w-an[q].y);
  }
  float vmax[NGT];
#pragma unroll 2
  for (int g=0; g<NGT; ++g){
    float g0=s_gt[g*4], g1=s_gt[g*4+1], g2=s_gt[g*4+2], g3=s_gt[g*4+3];
    float ga=s_ga[g];
    float bi=0.0f, bu=1.0f;                 // v=0 baseline
#pragma unroll
    for (int q=0; q<8; ++q){
      float lx=fmaxf(g0,an[q].x), ly=fmaxf(g1,an[q].y);
      float rx=fminf(g2,an[q].z), ry=fminf(g3,an[q].w);
      float iw=fmaxf(rx-lx,0.0f), ih=fmaxf(ry-ly,0.0f);
      float inter=iw*ih;
      float uni=fmaxf(ga+aA[q]-inter,1e-9f);
      if (inter*bu > bi*uni){ bi=inter; bu=uni; }
    }
    vmax[g] = bi/bu;
  }
  int lane = tid & 63;
#pragma unroll
  for (int g=0; g<NGT; ++g){
    float v = vmax[g];
    v = fmaxf(v, __shfl_xor(v, 1, 64));
    v = fmaxf(v, __shfl_xor(v, 2, 64));
    v = fmaxf(v, __shfl_xor(v, 4, 64));
    v = fmaxf(v, __shfl_xor(v, 8, 64));
    v = fmaxf(v, __shfl_xor(v,16, 64));
    v = fmaxf(v, __shfl_xor(v,32, 64));
    if (lane==0 && v > 0.0f) atomicMax(&s_best[g], __float_as_int(v));
  }
  __syncthreads();
  if (tid < NGT) atomicMax(&best[img*NGT + tid], s_best[tid]);
}

// ---------------- P1: refine level-1 histogram (if needed) ----------------
__global__ __launch_bounds__(256) void kP1(const float* __restrict__ logits,
                                           const u32* __restrict__ hist0,
                                           u32* __restrict__ hist1) {
  __shared__ u32 s_h[2048];
  __shared__ int s_i[8]; __shared__ u32 s_u[3];
  int img = blockIdx.y, tid = threadIdx.x;
  int d0,k0; u32 c0;
  pick2048(hist0 + img*2048, PRE, s_i, s_u, d0,k0,c0);
  if (c0 <= 2048u) return;                   // block-uniform
  for (int b=tid; b<2048; b+=256) s_h[b]=0u;
  __syncthreads();
  const float* sc = logits + (size_t)img*R_ANCH;
  for (int r = blockIdx.x*256 + tid; r < R_ANCH; r += NBLK*256){
    u64 key = make_key(sc[r], r);
    if ((int)(key>>53) == d0) atomicAdd(&s_h[(u32)(key>>42)&2047u], 1u);
  }
  __syncthreads();
  for (int b=tid; b<2048; b+=256){ u32 v=s_h[b]; if(v) atomicAdd(&hist1[img*2048+b], v); }
}

// ---------------- P2: refine level-2 histogram (rarely needed) ------------
__global__ __launch_bounds__(256) void kP2(const float* __restrict__ logits,
                                           const u32* __restrict__ hist0,
                                           const u32* __restrict__ hist1,
                                           u32* __restrict__ hist2) {
  __shared__ u32 s_h[2048];
  __shared__ int s_i[8]; __shared__ u32 s_u[3];
  int img = blockIdx.y, tid = threadIdx.x;
  int d0,k0; u32 c0;
  pick2048(hist0 + img*2048, PRE, s_i, s_u, d0,k0,c0);
  if (c0 <= 2048u) return;
  int d1,k1; u32 c1;
  pick2048(hist1 + img*2048, k0, s_i, s_u, d1,k1,c1);
  if (c1 <= 2048u) return;
  u64 p1 = ((u64)d0<<11) | (u64)d1;
  for (int b=tid; b<2048; b+=256) s_h[b]=0u;
  __syncthreads();
  const float* sc = logits + (size_t)img*R_ANCH;
  for (int r = blockIdx.x*256 + tid; r < R_ANCH; r += NBLK*256){
    u64 key = make_key(sc[r], r);
    if ((key>>42) == p1) atomicAdd(&s_h[(u32)(key>>31)&2047u], 1u);
  }
  __syncthreads();
  for (int b=tid; b<2048; b+=256){ u32 v=s_h[b]; if(v) atomicAdd(&hist2[img*2048+b], v); }
}

// ---------------- G: gather candidates, block-compacted -------------------
__global__ __launch_bounds__(256) void kGather(const float* __restrict__ logits,
    const u32* __restrict__ hist0, const u32* __restrict__ hist1,
    const u32* __restrict__ hist2, u64* __restrict__ cand, u32* __restrict__ gcnt) {
  __shared__ int s_i[8]; __shared__ u32 s_u[3];
  __shared__ u64 s_cand[2048];               // 16 KB staging
  __shared__ u32 s_cnt, s_base;
  int img = blockIdx.y, tid = threadIdx.x;
  if (tid==0) s_cnt = 0u;
  int d,kk; u32 c;
  pick2048(hist0 + img*2048, PRE, s_i, s_u, d,kk,c);   // has syncthreads
  u64 p = (u64)d; int L = 0;
  if (c > 2048u){
    pick2048(hist1 + img*2048, kk, s_i, s_u, d,kk,c);
    p = (p<<11)|(u64)d; L = 1;
    if (c > 2048u){
      pick2048(hist2 + img*2048, kk, s_i, s_u, d,kk,c);
      p = (p<<11)|(u64)d; L = 2;
    }
  }
  u64 T = p << (64 - 11*(L+1));              // total candidates <= 4047
  const float* sc = logits + (size_t)img*R_ANCH;
  int lane = tid & 63;
  for (int r = blockIdx.x*256 + tid; r < R_ANCH; r += NBLK*256){
    u64 key = make_key(sc[r], r);
    bool take = (key >= T);
    u64 b = __ballot(take);
    if (b){
      u32 base = 0;
      if (lane==0) base = atomicAdd(&s_cnt, (u32)__popcll(b));   // LDS atomic
      base = (u32)__shfl((int)base, 0, 64);
      if (take){
        u32 pos = base + (u32)__popcll(b & ((1ull<<lane)-1ull));
        if (pos < 2048u) s_cand[pos] = key;
        else {                               // never on this data; correctness net
          u32 gp = atomicAdd(&gcnt[img*GC_STRIDE], 1u);
          if (gp < 4096u) cand[(size_t)img*4096 + gp] = key;
        }
      }
    }
  }
  __syncthreads();
  u32 n = s_cnt < 2048u ? s_cnt : 2048u;
  if (tid==0) s_base = atomicAdd(&gcnt[img*GC_STRIDE], n);  // 1 atomic/block
  __syncthreads();
  u32 gb = s_base;
  for (u32 i=tid; i<n; i+=256)
    cand[(size_t)img*4096 + gb + i] = s_cand[i];
}

// ---------------- R: exact bucket-rank + epilogue (replaces bitonic) ------
// Keys unique -> rank(key) = #keys greater = (#keys in higher 11-bit bins)
// + (#same-bin keys greater). Histogram of <=4096 candidates + descending
// prefix scan + index scatter + tiny per-bin compare loops. O(n*binsize)
// instead of the bitonic's O(n log^2 n) LDS-pipe traffic (which was the
// 43 us wall: shfl = ds_bpermute shares the LDS pipe; 1 CU per image).
// Adversarial all-one-bin degenerates to O(n^2) in-LDS -- correct, slow,
// never hit with continuous scores.
__global__ __launch_bounds__(1024) void kRank(
    const u64* __restrict__ cand, const u32* __restrict__ gcnt,
    const float* __restrict__ epis, const float* __restrict__ alea,
    const float* __restrict__ deltas, const float* __restrict__ anchors,
    float* __restrict__ tb, float* __restrict__ tu, float* __restrict__ ts) {
  __shared__ u64 s_key[4096];                // 32 KB
  __shared__ u16 s_bidx[4096];               // 8 KB
  __shared__ u32 s_h[2048];                  // 8 KB
  __shared__ u32 s_off[2048];                // 8 KB (exclusive, then mutated)
  __shared__ u32 s_wsum[16];
  int tid = threadIdx.x, img = blockIdx.x;
  u32 cnt = gcnt[img*GC_STRIDE];
  if (cnt > 4096u) cnt = 4096u;
  const u64* cp = cand + (size_t)img*4096;
  for (int i=tid; i<4096; i+=1024) s_key[i] = (i < (int)cnt) ? cp[i] : 0ull;
  for (int b=tid; b<2048; b+=1024) s_h[b] = 0u;
  __syncthreads();
  for (int i=tid; i<(int)cnt; i+=1024)
    atomicAdd(&s_h[(u32)(s_key[i]>>53)], 1u);
  __syncthreads();
  // descending prefix over 2048 bins; thread t covers bins 2047-2t, 2046-2t
  {
    int b_hi = 2047 - 2*tid, b_lo = b_hi - 1;
    u32 h_hi = s_h[b_hi], h_lo = s_h[b_lo];
    u32 sum = h_hi + h_lo;
    u32 incl = sum;
    int lane = tid & 63, wv = tid >> 6;
    for (int off=1; off<64; off<<=1){
      u32 t = (u32)__shfl_up((int)incl, off, 64);
      if (lane >= off) incl += t;
    }
    if (lane==63) s_wsum[wv] = incl;
    __syncthreads();
    u32 base = 0;
    for (int w=0; w<wv; ++w) base += s_wsum[w];
    u32 excl = base + incl - sum;
    s_off[b_hi] = excl;
    s_off[b_lo] = excl + h_hi;
  }
  __syncthreads();
  // scatter candidate indices into bucket order (order within bin arbitrary)
  for (int i=tid; i<(int)cnt; i+=1024){
    u32 d = (u32)(s_key[i]>>53);
    u32 slot = atomicAdd(&s_off[d], 1u);     // post: s_off[d] = base + size
    s_bidx[slot] = (u16)i;
  }
  __syncthreads();
  // rank + epilogue
  for (int i=tid; i<(int)cnt; i+=1024){
    u64 my = s_key[i];
    u32 d = (u32)(my>>53);
    u32 size = s_h[d];
    u32 bs = s_off[d] - size;                // bucket base
    u32 rank = bs;
    for (u32 q=bs; q<bs+size; ++q)
      rank += (s_key[s_bidx[q]] > my) ? 1u : 0u;
    if (rank < PRE){
      int p = (int)rank;
      u32 idx = 0xFFFFFFFFu - (u32)(my & 0xFFFFFFFFull);
      ts[img*PRE + p] = dec_score(my);
      float4 a = ((const float4*)anchors)[idx];
      float4 dd = ((const float4*)deltas)[(size_t)img*R_ANCH + idx];
      float w = a.z - a.x, h = a.w - a.y;
      float cx = a.x + 0.5f*w, cy = a.y + 0.5f*h;
      float dw = fminf(dd.z, SCALE_CLAMP_F), dh = fminf(dd.w, SCALE_CLAMP_F);
      float pcx = dd.x*w + cx, pcy = dd.y*h + cy;
      float pw = expf(dw)*w, ph = expf(dh)*h;
      float x0 = fminf(fmaxf(pcx - 0.5f*pw, 0.0f), IMG_SZ);
      float y0 = fminf(fmaxf(pcy - 0.5f*ph, 0.0f), IMG_SZ);
      float x1 = fminf(fmaxf(pcx + 0.5f*pw, 0.0f), IMG_SZ);
      float y1 = fminf(fmaxf(pcy + 0.5f*ph, 0.0f), IMG_SZ);
      ((float4*)tb)[(size_t)img*PRE + p] = make_float4(x0,y0,x1,y1);
      size_t o = (size_t)img*R_ANCH + idx;
      ((float2*)tu)[(size_t)img*PRE + p] = make_float2(epis[o], alea[o]);
    }
  }
}

// ---------------- D: masks + sparse suppressor lists (EXACT IoU) ----------
__global__ __launch_bounds__(1024) void kD_mask(const float* __restrict__ tb,
                                                u64* __restrict__ maskLT,
                                                u32* __restrict__ scnt,
                                                u16* __restrict__ slist) {
  __shared__ float4 s_tile[64];
  int tid = threadIdx.x;
  int a = blockIdx.x, img = blockIdx.y;
  const float4* tbi = (const float4*)tb + (size_t)img*PRE;
  if (tid < 64){
    int i = a*64 + tid;
    s_tile[tid] = (i < PRE) ? tbi[i] : make_float4(0.f,0.f,0.f,0.f);
  }
  __syncthreads();
  u64* outp = maskLT + ((size_t)img*32 + a)*MROW;
  u32* cnts = scnt + (size_t)img*2048;
  u16* lst  = slist + (size_t)img*2048*SCAP;
  int bmax = min(64, PRE - a*64);
  for (int j = a*64 + tid; j < MROW; j += 1024){
    u64 m = 0ull;
    if (j < PRE){
      float4 B = tbi[j];
      int blim = min(bmax, j - a*64);        // only b with a*64+b < j
      for (int b = 0; b < blim; ++b){
        float4 A = s_tile[b];
        float v = iou_pair(A.x,A.y,A.z,A.w, B.x,B.y,B.z,B.w);
        m |= (u64)(v > NMS_T) << b;
      }
    }
    outp[j] = m;
    u64 mm = m;
    while (mm){
      int b = __builtin_ctzll(mm); mm &= mm - 1ull;
      u32 slot = atomicAdd(&cnts[j], 1u);
      if (slot < SCAP) lst[(size_t)j*SCAP + slot] = (u16)(a*64 + b);
    }
  }
}

// ---------------- E: greedy NMS — sparse Jacobi fixpoint, 1 block/img -----
__global__ __launch_bounds__(1024) void kE_nms(const u64* __restrict__ maskLT,
                                               const u32* __restrict__ scnt,
                                               const u16* __restrict__ slist,
                                               u64* __restrict__ keep) {
  __shared__ u64 s_list64[2048*SCAP/4];      // 64 KB staged lists
  __shared__ u16 s_cnt[2048];                // 4 KB
  __shared__ u8  kbuf[2][2048];              // 4 KB
  __shared__ u64 s_kw[32];
  __shared__ int s_change, s_ovf;
  int img = blockIdx.x, tid = threadIdx.x;
  const u64* gl = (const u64*)(slist + (size_t)img*2048*SCAP);
  for (int i=tid; i<2048*SCAP/4; i+=1024) s_list64[i] = gl[i];
  const u32* gc = scnt + (size_t)img*2048;
  for (int i=tid; i<2048; i+=1024) s_cnt[i] = (u16)gc[i];
  if (tid==0){ s_change = 0; s_ovf = 0; }
  __syncthreads();
  bool myovf = false;
#pragma unroll
  for (int q=0; q<2; ++q){
    int j = tid + q*1024;
    if (s_cnt[j] > SCAP) myovf = true;
    kbuf[0][j] = (j < PRE) ? 1 : 0;
  }
  if (myovf) s_ovf = 1;                      // benign race
  __syncthreads();
  const u64* MT = maskLT + (size_t)img*32*MROW;
  int cur = 0;
  for (int iter=0; iter<2048; ++iter){
    bool ovf = (s_ovf != 0);                 // stable after init barrier
    if (ovf && tid < 32){
      u64 w = 0ull;
      for (int b=0; b<64; ++b) w |= (u64)(kbuf[cur][tid*64+b] & 1) << b;
      s_kw[tid] = w;
    }
    __syncthreads();                         // A: s_change reset + kw visible
    bool changed = false;
#pragma unroll
    for (int q=0; q<2; ++q){
      int j = tid + q*1024;
      u8 old = kbuf[cur][j];
      u8 nk = (j < PRE) ? 1 : 0;
      if (nk){
        int cnt = s_cnt[j];
        if (cnt <= SCAP){
          const u16* lp = (const u16*)&s_list64[j*(SCAP/4)];
          for (int i=0; i<cnt; ++i){
            if (kbuf[cur][lp[i]]){ nk = 0; break; }
          }
        } else {
          int amax = j >> 6;
          for (int a=0; a<=amax; ++a){
            if (MT[(size_t)a*MROW + j] & s_kw[a]){ nk = 0; break; }
          }
        }
      }
      kbuf[1-cur][j] = nk;
      changed |= (nk != old);
    }
    if (changed) s_change = 1;
    __syncthreads();                         // B: all writes done
    int ch = s_change;
    __syncthreads();                         // C: all have read ch
    if (tid==0) s_change = 0;                // reset (visible by next A)
    if (!ch) break;                          // uniform
    cur ^= 1;
  }
  if (tid < 32){
    u64 w = 0ull;
    for (int b=0; b<64; ++b) w |= (u64)(kbuf[cur][tid*64+b] & 1) << b;
    keep[img*32 + tid] = w;
  }
}

// ---------------- L2lite: labels (division-light) + chunk counts ----------
__global__ __launch_bounds__(256) void kL2_label(
    const float* __restrict__ anchors, const float* __restrict__ gt,
    const int* __restrict__ best,
    signed char* __restrict__ label, int* __restrict__ cpos, int* __restrict__ cneg) {
  __shared__ float s_gt[NGT*4];
  __shared__ float s_ga[NGT];
  __shared__ float s_bg[NGT];
  __shared__ int s_w[8];
  int tid = threadIdx.x, img = blockIdx.y;
  int r = blockIdx.x*256 + tid;
  if (tid < NGT*4) s_gt[tid] = gt[img*NGT*4 + tid];
  if (tid < NGT){
    const float* g4 = gt + img*NGT*4 + tid*4;
    s_ga[tid] = (g4[2]-g4[0])*(g4[3]-g4[1]);
    s_bg[tid] = __int_as_float(best[img*NGT + tid]);
  }
  __syncthreads();
  float4 a = ((const float4*)anchors)[r];
  float aA = (a.z-a.x)*(a.w-a.y);
  float bi=-1.0f, bu=1.0f; bool lq = false;
#pragma unroll 4
  for (int g=0; g<NGT; ++g){
    float g0=s_gt[g*4], g1=s_gt[g*4+1], g2=s_gt[g*4+2], g3=s_gt[g*4+3];
    float lx=fmaxf(g0,a.x), ly=fmaxf(g1,a.y);
    float rx=fminf(g2,a.z), ry=fminf(g3,a.w);
    float iw=fmaxf(rx-lx,0.0f), ih=fmaxf(ry-ly,0.0f);
    float inter=iw*ih;
    float uni = fmaxf(s_ga[g] + aA - inter, 1e-9f);
    if (inter*bu > bi*uni){ bi=inter; bu=uni; }
    float bg = s_bg[g];
    lq = lq || ((inter >= (bg - 1e-7f)*uni) && (bg > 0.0f));
  }
  float vbest = bi/bu;
  int lab = lq ? 1 : (vbest >= 0.7f ? 1 : (vbest >= 0.3f ? -1 : 0));
  label[(size_t)img*R_ANCH + r] = (signed char)lab;
  u64 bp = __ballot(lab==1), bn = __ballot(lab==0);
  int wid = tid>>6, lane = tid&63;
  if (lane==0){ s_w[wid*2]=__popcll(bp); s_w[wid*2+1]=__popcll(bn); }
  __syncthreads();
  if (tid==0){
    cpos[img*NCHUNK + blockIdx.x] = s_w[0]+s_w[2]+s_w[4]+s_w[6];
    cneg[img*NCHUNK + blockIdx.x] = s_w[1]+s_w[3]+s_w[5]+s_w[7];
  }
}

// ---------------- L3: parallel per-image chunk-offset scan + quotas -------
__global__ __launch_bounds__(512) void kL3_scan(const int* __restrict__ cpos,
                                                const int* __restrict__ cneg,
                                                int* __restrict__ opos,
                                                int* __restrict__ oneg,
                                                int* __restrict__ quota) {
  __shared__ int s_p[8], s_n[8];
  int img = blockIdx.x, tid = threadIdx.x;
  int vp=0, vn=0;
  if (tid < NCHUNK){ vp = cpos[img*NCHUNK+tid]; vn = cneg[img*NCHUNK+tid]; }
  int lane = tid&63, w = tid>>6;
  int ip=vp, in_=vn;
  for (int off=1; off<64; off<<=1){
    int tp=__shfl_up(ip,off,64), tn=__shfl_up(in_,off,64);
    if (lane>=off){ ip+=tp; in_+=tn; }
  }
  if (lane==63){ s_p[w]=ip; s_n[w]=in_; }
  __syncthreads();
  int bp=0,bn=0;
  for (int ww=0; ww<w; ++ww){ bp+=s_p[ww]; bn+=s_n[ww]; }
  if (tid < NCHUNK){
    opos[img*NCHUNK+tid] = bp+ip-vp;
    oneg[img*NCHUNK+tid] = bn+in_-vn;
  }
  if (tid==0){
    int tp=0,tn=0;
    for (int ww=0; ww<8; ++ww){ tp+=s_p[ww]; tn+=s_n[ww]; }
    int np = tp<128?tp:128;
    quota[img*2]=np; quota[img*2+1]=256-np;
  }
}

// ---------------- L4: quota-sampled loss accumulation ---------------------
__global__ __launch_bounds__(256) void kL4_accum(
    const signed char* __restrict__ label, const float* __restrict__ nll_i,
    const float* __restrict__ loc_i, const int* __restrict__ opos,
    const int* __restrict__ oneg, const int* __restrict__ quota,
    float* __restrict__ acc) {
  __shared__ int s_wp[4], s_wn[4];
  __shared__ float s_red[8];
  int tid = threadIdx.x, img = blockIdx.y;
  int r = blockIdx.x*256 + tid;
  size_t o = (size_t)img*R_ANCH + r;
  int lab = label[o];
  bool pos = (lab==1), neg = (lab==0);
  u64 bp = __ballot(pos), bn = __ballot(neg);
  int wid = tid>>6, lane = tid&63;
  if (lane==0){ s_wp[wid]=__popcll(bp); s_wn[wid]=__popcll(bn); }
  __syncthreads();
  int pre_p = opos[img*NCHUNK + blockIdx.x];
  int pre_n = oneg[img*NCHUNK + blockIdx.x];
  for (int w=0; w<wid; ++w){ pre_p += s_wp[w]; pre_n += s_wn[w]; }
  u64 lm = (1ull<<lane) - 1ull;
  pre_p += __popcll(bp & lm);
  pre_n += __popcll(bn & lm);
  int np = quota[img*2], nn = quota[img*2+1];
  bool kp = pos && (pre_p < np);
  bool kn = neg && (pre_n < nn);
  float c_cls = (kp||kn) ? nll_i[o] : 0.0f;
  float c_loc = kp ? loc_i[o] : 0.0f;
  for (int of=32; of>0; of>>=1){
    c_cls += __shfl_down(c_cls, of, 64);
    c_loc += __shfl_down(c_loc, of, 64);
  }
  if (lane==0){ s_red[wid]=c_cls; s_red[4+wid]=c_loc; }
  __syncthreads();
  if (tid==0){
    float a = s_red[0]+s_red[1]+s_red[2]+s_red[3];
    float b = s_red[4]+s_red[5]+s_red[6]+s_red[7];
    if (a != 0.0f) atomicAdd(&acc[0], a);
    if (b != 0.0f) atomicAdd(&acc[1], b);
  }
}

// ---------------- F: stable compaction to 1000 + outputs ------------------
__global__ __launch_bounds__(256) void kF_final(
    const float* __restrict__ tb, const float* __restrict__ tu,
    const float* __restrict__ ts, const u64* __restrict__ keepw,
    const float* __restrict__ acc, float* __restrict__ out) {
  __shared__ int s_wk[4], s_wn[4];
  __shared__ int s_kc, s_runk, s_runn;
  int tid = threadIdx.x, img = blockIdx.x;
  int wid = tid>>6, lane = tid&63;
  const u64* kw = keepw + img*32;
  const float NEG_INF = __uint_as_float(0xff800000u);
  int cnt = 0;
  for (int c=0; c<8; ++c){
    int p = c*256 + tid;
    float4 b = ((const float4*)tb)[(size_t)img*PRE + p];
    bool kp = (p < PRE) && (((kw[p>>6]>>(p&63))&1ull)!=0ull) && (b.z > b.x) && (b.w > b.y);
    cnt += kp ? 1 : 0;
  }
  for (int of=32; of>0; of>>=1) cnt += __shfl_down(cnt, of, 64);
  if (lane==0) s_wk[wid] = cnt;
  __syncthreads();
  if (tid==0){ s_kc = s_wk[0]+s_wk[1]+s_wk[2]+s_wk[3]; s_runk=0; s_runn=0; }
  __syncthreads();
  int kc = s_kc;
  for (int c=0; c<8; ++c){
    int p = c*256 + tid;
    float4 b = ((const float4*)tb)[(size_t)img*PRE + p];
    bool kp = (p < PRE) && (((kw[p>>6]>>(p&63))&1ull)!=0ull) && (b.z > b.x) && (b.w > b.y);
    u64 bk = __ballot(kp), bn = __ballot(!kp);
    if (lane==0){ s_wk[wid]=__popcll(bk); s_wn[wid]=__popcll(bn); }
    __syncthreads();
    int pk = s_runk, pn = s_runn;
    for (int w=0; w<wid; ++w){ pk += s_wk[w]; pn += s_wn[w]; }
    u64 lm = (1ull<<lane) - 1ull;
    pk += __popcll(bk & lm);
    pn += __popcll(bn & lm);
    int slot = kp ? pk : (kc + pn);
    if (slot < POST && p < PRE){
      ((float4*)out)[img*POST + slot] = b;
      out[32000 + img*POST + slot] = kp ? ts[img*PRE + p] : NEG_INF;
      ((float2*)(out + 40000))[img*POST + slot] = ((const float2*)tu)[(size_t)img*PRE + p];
    }
    __syncthreads();
    if (tid==0){
      s_runk += s_wk[0]+s_wk[1]+s_wk[2]+s_wk[3];
      s_runn += s_wn[0]+s_wn[1]+s_wn[2]+s_wn[3];
    }
    __syncthreads();
  }
  if (img==0 && tid<2) out[56000+tid] = acc[tid] * (1.0f/2048.0f);
}

// ---------------- host-side launch ----------------------------------------
extern "C" void kernel_launch(void* const* d_in, const int* in_sizes, int n_in,
                              void* d_out, int out_size, void* d_ws, size_t ws_size,
                              hipStream_t stream) {
  const float* anchors = (const float*)d_in[0];
  const float* pi      = (const float*)d_in[1];
  const float* mu      = (const float*)d_in[2];
  const float* sigma   = (const float*)d_in[3];
  const float* deltas  = (const float*)d_in[4];
  const float* gt      = (const float*)d_in[5];
  float* out = (float*)d_out;

  char* ws = (char*)d_ws;
  size_t off = 0;
  auto alloc = [&](size_t bytes) -> void* {
    void* p = (void*)(ws + off);
    off += (bytes + 255) & ~(size_t)255;
    return p;
  };
  float* logits = (float*)alloc((size_t)NIMG*R_ANCH*4);
  float* epis   = (float*)alloc((size_t)NIMG*R_ANCH*4);
  float* alea   = (float*)alloc((size_t)NIMG*R_ANCH*4);
  float* nll    = (float*)alloc((size_t)NIMG*R_ANCH*4);
  float* loc    = (float*)alloc((size_t)NIMG*R_ANCH*4);
  float* tb     = (float*)alloc((size_t)NIMG*PRE*4*4);
  float* tu     = (float*)alloc((size_t)NIMG*PRE*2*4);
  float* ts     = (float*)alloc((size_t)NIMG*PRE*4);
  u64*   maskLT = (u64*)  alloc((size_t)NIMG*32*MROW*8);
  u16*   slist  = (u16*)  alloc((size_t)NIMG*2048*SCAP*2);
  u64*   keepw  = (u64*)  alloc((size_t)NIMG*32*8);
  u64*   cand   = (u64*)  alloc((size_t)NIMG*4096*8);
  int*   cpos   = (int*)  alloc((size_t)NIMG*NCHUNK*4);
  int*   cneg   = (int*)  alloc((size_t)NIMG*NCHUNK*4);
  int*   opos   = (int*)  alloc((size_t)NIMG*NCHUNK*4);
  int*   oneg   = (int*)  alloc((size_t)NIMG*NCHUNK*4);
  int*   quota  = (int*)  alloc((size_t)NIMG*2*4);
  // ---- contiguous zero region ----
  size_t zstart = off;
  u32*   hist0  = (u32*)  alloc((size_t)NIMG*2048*4);
  u32*   hist1  = (u32*)  alloc((size_t)NIMG*2048*4);
  u32*   hist2  = (u32*)  alloc((size_t)NIMG*2048*4);
  u32*   gcnt   = (u32*)  alloc((size_t)NIMG*GC_STRIDE*4);
  int*   best   = (int*)  alloc((size_t)NIMG*NGT*4);
  u32*   scnt   = (u32*)  alloc((size_t)NIMG*2048*4);
  float* acc    = (float*)alloc(8);
  int zwords = (int)((off - zstart) / 4);
  // label aliases logits: logits last read in kGather; kL2 runs after kE.
  signed char* label = (signed char*)logits;

  kZero<<<dim3(64), dim3(256), 0, stream>>>((u32*)(ws + zstart), zwords);
  kA_mdn<<<dim3(NCHUNK, NIMG), dim3(256), 0, stream>>>(pi, mu, sigma, logits, epis, alea,
                                                       hist0, anchors, gt, deltas, nll, loc);
  kL1_bestgt<<<dim3(NBLK, NIMG), dim3(256), 0, stream>>>(anchors, gt, best);
  kP1<<<dim3(NBLK, NIMG), dim3(256), 0, stream>>>(logits, hist0, hist1);
  kP2<<<dim3(NBLK, NIMG), dim3(256), 0, stream>>>(logits, hist0, hist1, hist2);
  kGather<<<dim3(NBLK, NIMG), dim3(256), 0, stream>>>(logits, hist0, hist1, hist2, cand, gcnt);
  kRank<<<dim3(NIMG), dim3(1024), 0, stream>>>(cand, gcnt, epis, alea, deltas, anchors, tb, tu, ts);
  kD_mask<<<dim3(32, NIMG), dim3(1024), 0, stream>>>(tb, maskLT, scnt, slist);
  kE_nms<<<dim3(NIMG), dim3(1024), 0, stream>>>(maskLT, scnt, slist, keepw);
  kL2_label<<<dim3(NCHUNK, NIMG), dim3(256), 0, stream>>>(anchors, gt, best, label, cpos, cneg);
  kL3_scan<<<dim3(NIMG), dim3(512), 0, stream>>>(cpos, cneg, opos, oneg, quota);
  kL4_accum<<<dim3(NCHUNK, NIMG), dim3(256), 0, stream>>>(label, nll, loc, opos, oneg, quota, acc);
  kF_final<<<dim3(NIMG), dim3(256), 0, stream>>>(tb, tu, ts, keepw, acc, out);
}

// Round 14
// 284.367 us; speedup vs baseline: 1.2997x; 1.2997x over previous
//
#include <hip/hip_runtime.h>
#include <cstdint>
#include <cstddef>

typedef unsigned long long u64;
typedef unsigned int u32;
typedef unsigned short u16;
typedef unsigned char u8;

#define R_ANCH 96000
#define NIMG   8
#define KMIX   5
#define PRE    2000
#define POST   1000
#define NGT    32
#define NCHUNK 375   // R_ANCH / 256
#define NBLK   48    // blocks per image for grid-stride scan kernels
#define MROW   2048  // maskLT row stride (padded PRE)
#define GC_STRIDE 16 // gcnt padding: 64 B per image (atomic-line isolation)
#define SCAP   16    // per-row suppressor-list capacity (overflow -> dense path)
#define BIG_TH 64    // kRank: bins larger than this go through level-1 split

#define IMG_SZ        1280.0f
#define NMS_T         0.7f
#define SCALE_CLAMP_F 4.135166556742356f
#define HALF_L2PI     0.9189385332046727f

__device__ __forceinline__ u64 make_key(float s, int r) {
  u32 u = __float_as_uint(s);
  u = (u & 0x80000000u) ? ~u : (u | 0x80000000u);
  return ((u64)u << 32) | (u64)(0xFFFFFFFFu - (u32)r);
}

__device__ __forceinline__ float dec_score(u64 key) {
  u32 o = (u32)(key >> 32);
  u32 bits = (o & 0x80000000u) ? (o ^ 0x80000000u) : ~o;
  return __uint_as_float(bits);
}

// EXACT-PATH IoU (NMS only): must match reference bit-for-bit since NMS
// decisions select whole boxes. Label-path kernels (kA/kL1/kL2) use
// division-free cross-multiplied compares instead (loss-only, tol 25.6).
__device__ __forceinline__ float iou_pair(float a0,float a1,float a2,float a3,
                                          float b0,float b1,float b2,float b3) {
#pragma clang fp contract(off)
  float areaA = (a2-a0)*(a3-a1);
  float areaB = (b2-b0)*(b3-b1);
  float lx=fmaxf(a0,b0), ly=fmaxf(a1,b1);
  float rx=fminf(a2,b2), ry=fminf(a3,b3);
  float iw=fmaxf(rx-lx,0.0f), ih=fmaxf(ry-ly,0.0f);
  float inter=iw*ih;
  return inter / fmaxf(areaA+areaB-inter, 1e-9f);
}

// pick: from a 2048-bin histogram (bin d high = higher keys), find the bin
// containing the k-th largest key. 256 threads. s_i >= 8 ints, s_u >= 3 u32.
__device__ __forceinline__ void pick2048(const u32* __restrict__ hist, int k,
                                         int* s_i, u32* s_u,
                                         int& d_out, int& k_out, u32& cnt_out) {
  int tid = threadIdx.x;
  int lane = tid & 63, w = tid >> 6;
  u32 h[8]; u32 ssum = 0;
#pragma unroll
  for (int i=0;i<8;++i){ h[i] = hist[2047 - (tid*8 + i)]; ssum += h[i]; }
  u32 incl = ssum;
  for (int off=1; off<64; off<<=1){
    u32 t = (u32)__shfl_up((int)incl, off, 64);
    if (lane >= off) incl += t;
  }
  if (lane==63) s_i[w] = (int)incl;
  __syncthreads();
  u32 base = 0;
  for (int ww=0; ww<w; ++ww) base += (u32)s_i[ww];
  u32 run = base + incl - ssum;              // exclusive prefix (descending keys)
#pragma unroll
  for (int i=0;i<8;++i){
    u32 nr = run + h[i];
    if (run < (u32)k && nr >= (u32)k){       // unique crossing thread
      s_u[0] = (u32)(2047 - (tid*8+i));
      s_u[1] = (u32)k - run;
      s_u[2] = h[i];
    }
    run = nr;
  }
  __syncthreads();
  d_out = (int)s_u[0]; k_out = (int)s_u[1]; cnt_out = s_u[2];
  __syncthreads();
}

// descending exclusive prefix over 2048 bins, 1024 threads (2 bins/thread).
// Caller must __syncthreads() before (h ready) and after (off ready).
__device__ __forceinline__ void scan2048_desc(const u32* __restrict__ h,
                                              u32* __restrict__ off,
                                              u32* __restrict__ wsum, int tid) {
  int b_hi = 2047 - 2*tid, b_lo = b_hi - 1;
  u32 h_hi = h[b_hi], h_lo = h[b_lo];
  u32 sum = h_hi + h_lo;
  u32 incl = sum;
  int lane = tid & 63, wv = tid >> 6;
  for (int o=1; o<64; o<<=1){
    u32 t = (u32)__shfl_up((int)incl, o, 64);
    if (lane >= o) incl += t;
  }
  if (lane==63) wsum[wv] = incl;
  __syncthreads();
  u32 base = 0;
  for (int w=0; w<wv; ++w) base += wsum[w];
  u32 excl = base + incl - sum;
  off[b_hi] = excl;
  off[b_lo] = excl + h_hi;
}

// ---------------- zero: contiguous workspace region -----------------------
__global__ void kZero(u32* z, int nwords) {
  for (int i = blockIdx.x*256 + threadIdx.x; i < nwords; i += gridDim.x*256)
    z[i] = 0u;
}

// ---------------- A: MDN moments + hist0 + per-anchor NLL/loc -------------
__global__ __launch_bounds__(256) void kA_mdn(
    const float* __restrict__ pi, const float* __restrict__ mu,
    const float* __restrict__ sigma, float* __restrict__ logits,
    float* __restrict__ epis, float* __restrict__ alea,
    u32* __restrict__ hist0,
    const float* __restrict__ anchors, const float* __restrict__ gt,
    const float* __restrict__ deltas,
    float* __restrict__ nll_o, float* __restrict__ loc_o) {
  __shared__ u32 s_h[2048];
  __shared__ float s_gt[NGT*4];
  int tid = threadIdx.x;
  int r = blockIdx.x*256 + tid;
  int img = blockIdx.y;
  for (int b=tid; b<2048; b+=256) s_h[b]=0u;
  if (tid < NGT*4) s_gt[tid] = gt[img*NGT*4 + tid];
  size_t base = (size_t)img*KMIX*R_ANCH + r;
  float p[KMIX], m[KMIX], s[KMIX];
#pragma unroll
  for (int k=0;k<KMIX;k++){
    p[k]=pi[base+(size_t)k*R_ANCH];
    m[k]=mu[base+(size_t)k*R_ANCH];
    s[k]=sigma[base+(size_t)k*R_ANCH];
  }
  float mx = p[0];
#pragma unroll
  for (int k=1;k<KMIX;k++) mx = fmaxf(mx,p[k]);
  float e[KMIX]; float sum = 0.0f;
#pragma unroll
  for (int k=0;k<KMIX;k++){ e[k]=expf(p[k]-mx); sum += e[k]; }
  float w[KMIX]; float lg = 0.0f;
#pragma unroll
  for (int k=0;k<KMIX;k++){ w[k]=e[k]/sum; lg += w[k]*m[k]; }
  float ep = 0.0f, al = 0.0f;
#pragma unroll
  for (int k=0;k<KMIX;k++){ float d=m[k]-lg; ep += w[k]*d*d; al += w[k]*s[k]*s[k]; }
  size_t o = (size_t)img*R_ANCH + r;
  logits[o]=lg; epis[o]=ep; alea[o]=al;
  __syncthreads();                           // s_h zero + s_gt complete
  u64 key = make_key(lg, r);
  atomicAdd(&s_h[(u32)(key>>53)], 1u);
  // per-anchor best IoU via cross-mult argmax (division-free)
  float4 a = ((const float4*)anchors)[r];
  float aA = (a.z-a.x)*(a.w-a.y);
  float bi = -1.0f, bu = 1.0f; int idx = 0;
#pragma unroll 4
  for (int g=0; g<NGT; ++g){
    float g0=s_gt[g*4], g1=s_gt[g*4+1], g2=s_gt[g*4+2], g3=s_gt[g*4+3];
    float ga=(g2-g0)*(g3-g1);
    float lx=fmaxf(g0,a.x), ly=fmaxf(g1,a.y);
    float rx=fminf(g2,a.z), ry=fminf(g3,a.w);
    float iw=fmaxf(rx-lx,0.0f), ih=fmaxf(ry-ly,0.0f);
    float inter=iw*ih;
    float uni = fmaxf(ga + aA - inter, 1e-9f);
    if (inter*bu > bi*uni){ bi=inter; bu=uni; idx=g; }
  }
  float vbest = bi/bu;
  // NLL (identical arithmetic to reference path)
  float lsum = logf(sum);
  float t_ = fminf(fmaxf(vbest, 0.0f), 1.0f);
  float comp[KMIX];
#pragma unroll
  for (int k=0;k<KMIX;k++){
    float z = (t_ - m[k]) / s[k];
    comp[k] = (p[k]-mx-lsum) - 0.5f*z*z - logf(s[k]) - HALF_L2PI;
  }
  float cm = comp[0];
#pragma unroll
  for (int k=1;k<KMIX;k++) cm = fmaxf(cm, comp[k]);
  float se = 0.0f;
#pragma unroll
  for (int k=0;k<KMIX;k++) se += expf(comp[k]-cm);
  float nll = -(cm + logf(se));
  // loc L1 vs matched gt
  const float* gb = &s_gt[idx*4];
  float sw = a.z-a.x, sh = a.w-a.y;
  float scx = a.x+0.5f*sw, scy = a.y+0.5f*sh;
  float tw = gb[2]-gb[0], th = gb[3]-gb[1];
  float tcx = gb[0]+0.5f*tw, tcy = gb[1]+0.5f*th;
  float4 d = ((const float4*)deltas)[(size_t)img*R_ANCH + r];
  float loc = fabsf(d.x-(tcx-scx)/sw) + fabsf(d.y-(tcy-scy)/sh)
            + fabsf(d.z-logf(tw/sw)) + fabsf(d.w-logf(th/sh));
  nll_o[o] = nll; loc_o[o] = loc;
  __syncthreads();
  for (int b=tid; b<2048; b+=256){ u32 v=s_h[b]; if(v) atomicAdd(&hist0[img*2048+b], v); }
}

// ---------------- L1: best IoU per GT — cross-mult, 1 div per (thread,g) --
__global__ __launch_bounds__(256) void kL1_bestgt(const float* __restrict__ anchors,
                                                  const float* __restrict__ gt,
                                                  int* __restrict__ best) {
  __shared__ float s_gt[NGT*4];
  __shared__ float s_ga[NGT];
  __shared__ int s_best[NGT];
  int tid = threadIdx.x, img = blockIdx.y;
  if (tid < NGT*4) s_gt[tid] = gt[img*NGT*4 + tid];
  if (tid < NGT){
    const float* g4 = gt + img*NGT*4 + tid*4;
    s_ga[tid] = (g4[2]-g4[0])*(g4[3]-g4[1]);
    s_best[tid] = 0;
  }
  __syncthreads();
  float4 an[8]; float aA[8];
#pragma unroll
  for (int q=0; q<8; ++q){
    int r = blockIdx.x*256 + tid + q*(NBLK*256);
    an[q] = (r < R_ANCH) ? ((const float4*)anchors)[r]
                         : make_float4(0.f,0.f,0.f,0.f);   // IoU=0, inert
    aA[q] = (an[q].z-an[q].x)*(an[q].w-an[q].y);
  }
  float vmax[NGT];
#pragma unroll 2
  for (int g=0; g<NGT; ++g){
    float g0=s_gt[g*4], g1=s_gt[g*4+1], g2=s_gt[g*4+2], g3=s_gt[g*4+3];
    float ga=s_ga[g];
    float bi=0.0f, bu=1.0f;                 // v=0 baseline
#pragma unroll
    for (int q=0; q<8; ++q){
      float lx=fmaxf(g0,an[q].x), ly=fmaxf(g1,an[q].y);
      float rx=fminf(g2,an[q].z), ry=fminf(g3,an[q].w);
      float iw=fmaxf(rx-lx,0.0f), ih=fmaxf(ry-ly,0.0f);
      float inter=iw*ih;
      float uni=fmaxf(ga+aA[q]-inter,1e-9f);
      if (inter*bu > bi*uni){ bi=inter; bu=uni; }
    }
    vmax[g] = bi/bu;
  }
  int lane = tid & 63;
#pragma unroll
  for (int g=0; g<NGT; ++g){
    float v = vmax[g];
    v = fmaxf(v, __shfl_xor(v, 1, 64));
    v = fmaxf(v, __shfl_xor(v, 2, 64));
    v = fmaxf(v, __shfl_xor(v, 4, 64));
    v = fmaxf(v, __shfl_xor(v, 8, 64));
    v = fmaxf(v, __shfl_xor(v,16, 64));
    v = fmaxf(v, __shfl_xor(v,32, 64));
    if (lane==0 && v > 0.0f) atomicMax(&s_best[g], __float_as_int(v));
  }
  __syncthreads();
  if (tid < NGT) atomicMax(&best[img*NGT + tid], s_best[tid]);
}

// ---------------- P1: refine level-1 histogram (if needed) ----------------
__global__ __launch_bounds__(256) void kP1(const float* __restrict__ logits,
                                           const u32* __restrict__ hist0,
                                           u32* __restrict__ hist1) {
  __shared__ u32 s_h[2048];
  __shared__ int s_i[8]; __shared__ u32 s_u[3];
  int img = blockIdx.y, tid = threadIdx.x;
  int d0,k0; u32 c0;
  pick2048(hist0 + img*2048, PRE, s_i, s_u, d0,k0,c0);
  if (c0 <= 2048u) return;                   // block-uniform
  for (int b=tid; b<2048; b+=256) s_h[b]=0u;
  __syncthreads();
  const float* sc = logits + (size_t)img*R_ANCH;
  for (int r = blockIdx.x*256 + tid; r < R_ANCH; r += NBLK*256){
    u64 key = make_key(sc[r], r);
    if ((int)(key>>53) == d0) atomicAdd(&s_h[(u32)(key>>42)&2047u], 1u);
  }
  __syncthreads();
  for (int b=tid; b<2048; b+=256){ u32 v=s_h[b]; if(v) atomicAdd(&hist1[img*2048+b], v); }
}

// ---------------- P2: refine level-2 histogram (rarely needed) ------------
__global__ __launch_bounds__(256) void kP2(const float* __restrict__ logits,
                                           const u32* __restrict__ hist0,
                                           const u32* __restrict__ hist1,
                                           u32* __restrict__ hist2) {
  __shared__ u32 s_h[2048];
  __shared__ int s_i[8]; __shared__ u32 s_u[3];
  int img = blockIdx.y, tid = threadIdx.x;
  int d0,k0; u32 c0;
  pick2048(hist0 + img*2048, PRE, s_i, s_u, d0,k0,c0);
  if (c0 <= 2048u) return;
  int d1,k1; u32 c1;
  pick2048(hist1 + img*2048, k0, s_i, s_u, d1,k1,c1);
  if (c1 <= 2048u) return;
  u64 p1 = ((u64)d0<<11) | (u64)d1;
  for (int b=tid; b<2048; b+=256) s_h[b]=0u;
  __syncthreads();
  const float* sc = logits + (size_t)img*R_ANCH;
  for (int r = blockIdx.x*256 + tid; r < R_ANCH; r += NBLK*256){
    u64 key = make_key(sc[r], r);
    if ((key>>42) == p1) atomicAdd(&s_h[(u32)(key>>31)&2047u], 1u);
  }
  __syncthreads();
  for (int b=tid; b<2048; b+=256){ u32 v=s_h[b]; if(v) atomicAdd(&hist2[img*2048+b], v); }
}

// ---------------- G: gather candidates, block-compacted -------------------
__global__ __launch_bounds__(256) void kGather(const float* __restrict__ logits,
    const u32* __restrict__ hist0, const u32* __restrict__ hist1,
    const u32* __restrict__ hist2, u64* __restrict__ cand, u32* __restrict__ gcnt) {
  __shared__ int s_i[8]; __shared__ u32 s_u[3];
  __shared__ u64 s_cand[2048];               // 16 KB staging
  __shared__ u32 s_cnt, s_base;
  int img = blockIdx.y, tid = threadIdx.x;
  if (tid==0) s_cnt = 0u;
  int d,kk; u32 c;
  pick2048(hist0 + img*2048, PRE, s_i, s_u, d,kk,c);   // has syncthreads
  u64 p = (u64)d; int L = 0;
  if (c > 2048u){
    pick2048(hist1 + img*2048, kk, s_i, s_u, d,kk,c);
    p = (p<<11)|(u64)d; L = 1;
    if (c > 2048u){
      pick2048(hist2 + img*2048, kk, s_i, s_u, d,kk,c);
      p = (p<<11)|(u64)d; L = 2;
    }
  }
  u64 T = p << (64 - 11*(L+1));              // total candidates <= 4047
  const float* sc = logits + (size_t)img*R_ANCH;
  int lane = tid & 63;
  for (int r = blockIdx.x*256 + tid; r < R_ANCH; r += NBLK*256){
    u64 key = make_key(sc[r], r);
    bool take = (key >= T);
    u64 b = __ballot(take);
    if (b){
      u32 base = 0;
      if (lane==0) base = atomicAdd(&s_cnt, (u32)__popcll(b));   // LDS atomic
      base = (u32)__shfl((int)base, 0, 64);
      if (take){
        u32 pos = base + (u32)__popcll(b & ((1ull<<lane)-1ull));
        if (pos < 2048u) s_cand[pos] = key;
        else {                               // never on this data; correctness net
          u32 gp = atomicAdd(&gcnt[img*GC_STRIDE], 1u);
          if (gp < 4096u) cand[(size_t)img*4096 + gp] = key;
        }
      }
    }
  }
  __syncthreads();
  u32 n = s_cnt < 2048u ? s_cnt : 2048u;
  if (tid==0) s_base = atomicAdd(&gcnt[img*GC_STRIDE], n);  // 1 atomic/block
  __syncthreads();
  u32 gb = s_base;
  for (u32 i=tid; i<n; i+=256)
    cand[(size_t)img*4096 + gb + i] = s_cand[i];
}

// ---------------- R: hierarchical exact bucket-rank + epilogue ------------
// R13 failure: candidates concentrate in 1-few digit0 bins (selection IS a
// bin boundary), so flat per-bin compare loops were O(size^2)=millions of
// LDS gathers. Fix: bins > BIG_TH members get a sequential level-1 split by
// digit1 (bits 52..42) -> sub-bins of ~1-3; compare loops become trivial.
// Bins with base >= PRE pruned (can't contribute output ranks). Exact.
__global__ __launch_bounds__(1024) void kRank(
    const u64* __restrict__ cand, const u32* __restrict__ gcnt,
    const float* __restrict__ epis, const float* __restrict__ alea,
    const float* __restrict__ deltas, const float* __restrict__ anchors,
    float* __restrict__ tb, float* __restrict__ tu, float* __restrict__ ts) {
  __shared__ u64 s_key[4096];                // 32 KB
  __shared__ u16 s_idx0[4096];               // 8 KB
  __shared__ u16 s_idx1[4096];               // 8 KB (per big bin, reused)
  __shared__ u32 s_h0[2048];                 // 8 KB
  __shared__ u32 s_off0[2048];               // 8 KB (excl; scatter makes base+size)
  __shared__ u32 s_h1[2048];                 // 8 KB
  __shared__ u32 s_off1[2048];               // 8 KB
  __shared__ u32 s_wsum[16];
  __shared__ u32 s_nbig;
  __shared__ u16 s_big[64];
  int tid = threadIdx.x, img = blockIdx.x;
  u32 cnt = gcnt[img*GC_STRIDE];
  if (cnt > 4096u) cnt = 4096u;
  const u64* cp = cand + (size_t)img*4096;
  for (int i=tid; i<4096; i+=1024) s_key[i] = (i < (int)cnt) ? cp[i] : 0ull;
  for (int b=tid; b<2048; b+=1024){ s_h0[b] = 0u; }
  if (tid==0) s_nbig = 0u;
  __syncthreads();
  for (int i=tid; i<(int)cnt; i+=1024)
    atomicAdd(&s_h0[(u32)(s_key[i]>>53)], 1u);
  __syncthreads();
  scan2048_desc(s_h0, s_off0, s_wsum, tid);
  __syncthreads();
  // collect big bins that can contribute ranks < PRE
  for (int b=tid; b<2048; b+=1024){
    u32 sz = s_h0[b];
    if (sz > BIG_TH && s_off0[b] < PRE){
      u32 q = atomicAdd(&s_nbig, 1u);
      if (q < 64u) s_big[q] = (u16)b;
    }
  }
  // scatter candidates into digit0-bucket order
  for (int i=tid; i<(int)cnt; i+=1024){
    u32 d = (u32)(s_key[i]>>53);
    u32 slot = atomicAdd(&s_off0[d], 1u);    // post: s_off0[d] = base + size
    s_idx0[slot] = (u16)i;
  }
  __syncthreads();
  // epilogue writer
  auto emit = [&](u64 my, u32 rank){
    if (rank < PRE){
      int p = (int)rank;
      u32 idx = 0xFFFFFFFFu - (u32)(my & 0xFFFFFFFFull);
      ts[img*PRE + p] = dec_score(my);
      float4 a = ((const float4*)anchors)[idx];
      float4 dd = ((const float4*)deltas)[(size_t)img*R_ANCH + idx];
      float w = a.z - a.x, h = a.w - a.y;
      float cx = a.x + 0.5f*w, cy = a.y + 0.5f*h;
      float dw = fminf(dd.z, SCALE_CLAMP_F), dh = fminf(dd.w, SCALE_CLAMP_F);
      float pcx = dd.x*w + cx, pcy = dd.y*h + cy;
      float pw = expf(dw)*w, ph = expf(dh)*h;
      float x0 = fminf(fmaxf(pcx - 0.5f*pw, 0.0f), IMG_SZ);
      float y0 = fminf(fmaxf(pcy - 0.5f*ph, 0.0f), IMG_SZ);
      float x1 = fminf(fmaxf(pcx + 0.5f*pw, 0.0f), IMG_SZ);
      float y1 = fminf(fmaxf(pcy + 0.5f*ph, 0.0f), IMG_SZ);
      ((float4*)tb)[(size_t)img*PRE + p] = make_float4(x0,y0,x1,y1);
      size_t o = (size_t)img*R_ANCH + idx;
      ((float2*)tu)[(size_t)img*PRE + p] = make_float2(epis[o], alea[o]);
    }
  };
  // small bins: direct compare loop (size <= BIG_TH)
  for (int i=tid; i<(int)cnt; i+=1024){
    u64 my = s_key[i];
    u32 d = (u32)(my>>53);
    u32 size = s_h0[d];
    if (size > BIG_TH) continue;             // handled below
    u32 bs = s_off0[d] - size;
    if (bs >= PRE) continue;                 // cannot produce rank < PRE
    u32 rank = bs;
    for (u32 q=bs; q<bs+size; ++q)
      rank += (s_key[s_idx0[q]] > my) ? 1u : 0u;
    emit(my, rank);
  }
  __syncthreads();
  u32 nbig = s_nbig < 64u ? s_nbig : 64u;
  for (u32 bb=0; bb<nbig; ++bb){             // block-uniform sequential loop
    u32 B = s_big[bb];
    u32 size = s_h0[B];
    u32 base0 = s_off0[B] - size;
    for (int b=tid; b<2048; b+=1024) s_h1[b] = 0u;
    __syncthreads();
    for (u32 q=tid; q<size; q+=1024){
      u64 k = s_key[s_idx0[base0+q]];
      atomicAdd(&s_h1[(u32)(k>>42)&2047u], 1u);
    }
    __syncthreads();
    scan2048_desc(s_h1, s_off1, s_wsum, tid);
    __syncthreads();
    for (u32 q=tid; q<size; q+=1024){
      u16 ci = s_idx0[base0+q];
      u64 k = s_key[ci];
      u32 slot = atomicAdd(&s_off1[(u32)(k>>42)&2047u], 1u);
      s_idx1[slot] = ci;
    }
    __syncthreads();
    for (u32 q=tid; q<size; q+=1024){
      u16 ci = s_idx1[q];
      u64 my = s_key[ci];
      u32 d1 = (u32)(my>>42)&2047u;
      u32 ssz = s_h1[d1];
      u32 sbs = s_off1[d1] - ssz;            // sub-bin base (within bin)
      u32 rank = base0 + sbs;
      for (u32 t2=sbs; t2<sbs+ssz; ++t2)
        rank += (s_key[s_idx1[t2]] > my) ? 1u : 0u;
      emit(my, rank);
    }
    __syncthreads();                         // s_h1/s_off1/s_idx1 reuse
  }
}

// ---------------- D: masks + sparse suppressor lists (EXACT IoU) ----------
__global__ __launch_bounds__(1024) void kD_mask(const float* __restrict__ tb,
                                                u64* __restrict__ maskLT,
                                                u32* __restrict__ scnt,
                                                u16* __restrict__ slist) {
  __shared__ float4 s_tile[64];
  int tid = threadIdx.x;
  int a = blockIdx.x, img = blockIdx.y;
  const float4* tbi = (const float4*)tb + (size_t)img*PRE;
  if (tid < 64){
    int i = a*64 + tid;
    s_tile[tid] = (i < PRE) ? tbi[i] : make_float4(0.f,0.f,0.f,0.f);
  }
  __syncthreads();
  u64* outp = maskLT + ((size_t)img*32 + a)*MROW;
  u32* cnts = scnt + (size_t)img*2048;
  u16* lst  = slist + (size_t)img*2048*SCAP;
  int bmax = min(64, PRE - a*64);
  for (int j = a*64 + tid; j < MROW; j += 1024){
    u64 m = 0ull;
    if (j < PRE){
      float4 B = tbi[j];
      int blim = min(bmax, j - a*64);        // only b with a*64+b < j
      for (int b = 0; b < blim; ++b){
        float4 A = s_tile[b];
        float v = iou_pair(A.x,A.y,A.z,A.w, B.x,B.y,B.z,B.w);
        m |= (u64)(v > NMS_T) << b;
      }
    }
    outp[j] = m;
    u64 mm = m;
    while (mm){
      int b = __builtin_ctzll(mm); mm &= mm - 1ull;
      u32 slot = atomicAdd(&cnts[j], 1u);
      if (slot < SCAP) lst[(size_t)j*SCAP + slot] = (u16)(a*64 + b);
    }
  }
}

// ---------------- E: greedy NMS — sparse Jacobi fixpoint, 1 block/img -----
__global__ __launch_bounds__(1024) void kE_nms(const u64* __restrict__ maskLT,
                                               const u32* __restrict__ scnt,
                                               const u16* __restrict__ slist,
                                               u64* __restrict__ keep) {
  __shared__ u64 s_list64[2048*SCAP/4];      // 64 KB staged lists
  __shared__ u16 s_cnt[2048];                // 4 KB
  __shared__ u8  kbuf[2][2048];              // 4 KB
  __shared__ u64 s_kw[32];
  __shared__ int s_change, s_ovf;
  int img = blockIdx.x, tid = threadIdx.x;
  const u64* gl = (const u64*)(slist + (size_t)img*2048*SCAP);
  for (int i=tid; i<2048*SCAP/4; i+=1024) s_list64[i] = gl[i];
  const u32* gc = scnt + (size_t)img*2048;
  for (int i=tid; i<2048; i+=1024) s_cnt[i] = (u16)gc[i];
  if (tid==0){ s_change = 0; s_ovf = 0; }
  __syncthreads();
  bool myovf = false;
#pragma unroll
  for (int q=0; q<2; ++q){
    int j = tid + q*1024;
    if (s_cnt[j] > SCAP) myovf = true;
    kbuf[0][j] = (j < PRE) ? 1 : 0;
  }
  if (myovf) s_ovf = 1;                      // benign race
  __syncthreads();
  const u64* MT = maskLT + (size_t)img*32*MROW;
  int cur = 0;
  for (int iter=0; iter<2048; ++iter){
    bool ovf = (s_ovf != 0);                 // stable after init barrier
    if (ovf && tid < 32){
      u64 w = 0ull;
      for (int b=0; b<64; ++b) w |= (u64)(kbuf[cur][tid*64+b] & 1) << b;
      s_kw[tid] = w;
    }
    __syncthreads();                         // A: s_change reset + kw visible
    bool changed = false;
#pragma unroll
    for (int q=0; q<2; ++q){
      int j = tid + q*1024;
      u8 old = kbuf[cur][j];
      u8 nk = (j < PRE) ? 1 : 0;
      if (nk){
        int cnt = s_cnt[j];
        if (cnt <= SCAP){
          const u16* lp = (const u16*)&s_list64[j*(SCAP/4)];
          for (int i=0; i<cnt; ++i){
            if (kbuf[cur][lp[i]]){ nk = 0; break; }
          }
        } else {
          int amax = j >> 6;
          for (int a=0; a<=amax; ++a){
            if (MT[(size_t)a*MROW + j] & s_kw[a]){ nk = 0; break; }
          }
        }
      }
      kbuf[1-cur][j] = nk;
      changed |= (nk != old);
    }
    if (changed) s_change = 1;
    __syncthreads();                         // B: all writes done
    int ch = s_change;
    __syncthreads();                         // C: all have read ch
    if (tid==0) s_change = 0;                // reset (visible by next A)
    if (!ch) break;                          // uniform
    cur ^= 1;
  }
  if (tid < 32){
    u64 w = 0ull;
    for (int b=0; b<64; ++b) w |= (u64)(kbuf[cur][tid*64+b] & 1) << b;
    keep[img*32 + tid] = w;
  }
}

// ---------------- L2lite: labels (division-light) + chunk counts ----------
__global__ __launch_bounds__(256) void kL2_label(
    const float* __restrict__ anchors, const float* __restrict__ gt,
    const int* __restrict__ best,
    signed char* __restrict__ label, int* __restrict__ cpos, int* __restrict__ cneg) {
  __shared__ float s_gt[NGT*4];
  __shared__ float s_ga[NGT];
  __shared__ float s_bg[NGT];
  __shared__ int s_w[8];
  int tid = threadIdx.x, img = blockIdx.y;
  int r = blockIdx.x*256 + tid;
  if (tid < NGT*4) s_gt[tid] = gt[img*NGT*4 + tid];
  if (tid < NGT){
    const float* g4 = gt + img*NGT*4 + tid*4;
    s_ga[tid] = (g4[2]-g4[0])*(g4[3]-g4[1]);
    s_bg[tid] = __int_as_float(best[img*NGT + tid]);
  }
  __syncthreads();
  float4 a = ((const float4*)anchors)[r];
  float aA = (a.z-a.x)*(a.w-a.y);
  float bi=-1.0f, bu=1.0f; bool lq = false;
#pragma unroll 4
  for (int g=0; g<NGT; ++g){
    float g0=s_gt[g*4], g1=s_gt[g*4+1], g2=s_gt[g*4+2], g3=s_gt[g*4+3];
    float lx=fmaxf(g0,a.x), ly=fmaxf(g1,a.y);
    float rx=fminf(g2,a.z), ry=fminf(g3,a.w);
    float iw=fmaxf(rx-lx,0.0f), ih=fmaxf(ry-ly,0.0f);
    float inter=iw*ih;
    float uni = fmaxf(s_ga[g] + aA - inter, 1e-9f);
    if (inter*bu > bi*uni){ bi=inter; bu=uni; }
    float bg = s_bg[g];
    lq = lq || ((inter >= (bg - 1e-7f)*uni) && (bg > 0.0f));
  }
  float vbest = bi/bu;
  int lab = lq ? 1 : (vbest >= 0.7f ? 1 : (vbest >= 0.3f ? -1 : 0));
  label[(size_t)img*R_ANCH + r] = (signed char)lab;
  u64 bp = __ballot(lab==1), bn = __ballot(lab==0);
  int wid = tid>>6, lane = tid&63;
  if (lane==0){ s_w[wid*2]=__popcll(bp); s_w[wid*2+1]=__popcll(bn); }
  __syncthreads();
  if (tid==0){
    cpos[img*NCHUNK + blockIdx.x] = s_w[0]+s_w[2]+s_w[4]+s_w[6];
    cneg[img*NCHUNK + blockIdx.x] = s_w[1]+s_w[3]+s_w[5]+s_w[7];
  }
}

// ---------------- L3: parallel per-image chunk-offset scan + quotas -------
__global__ __launch_bounds__(512) void kL3_scan(const int* __restrict__ cpos,
                                                const int* __restrict__ cneg,
                                                int* __restrict__ opos,
                                                int* __restrict__ oneg,
                                                int* __restrict__ quota) {
  __shared__ int s_p[8], s_n[8];
  int img = blockIdx.x, tid = threadIdx.x;
  int vp=0, vn=0;
  if (tid < NCHUNK){ vp = cpos[img*NCHUNK+tid]; vn = cneg[img*NCHUNK+tid]; }
  int lane = tid&63, w = tid>>6;
  int ip=vp, in_=vn;
  for (int off=1; off<64; off<<=1){
    int tp=__shfl_up(ip,off,64), tn=__shfl_up(in_,off,64);
    if (lane>=off){ ip+=tp; in_+=tn; }
  }
  if (lane==63){ s_p[w]=ip; s_n[w]=in_; }
  __syncthreads();
  int bp=0,bn=0;
  for (int ww=0; ww<w; ++ww){ bp+=s_p[ww]; bn+=s_n[ww]; }
  if (tid < NCHUNK){
    opos[img*NCHUNK+tid] = bp+ip-vp;
    oneg[img*NCHUNK+tid] = bn+in_-vn;
  }
  if (tid==0){
    int tp=0,tn=0;
    for (int ww=0; ww<8; ++ww){ tp+=s_p[ww]; tn+=s_n[ww]; }
    int np = tp<128?tp:128;
    quota[img*2]=np; quota[img*2+1]=256-np;
  }
}

// ---------------- L4: quota-sampled loss accumulation ---------------------
__global__ __launch_bounds__(256) void kL4_accum(
    const signed char* __restrict__ label, const float* __restrict__ nll_i,
    const float* __restrict__ loc_i, const int* __restrict__ opos,
    const int* __restrict__ oneg, const int* __restrict__ quota,
    float* __restrict__ acc) {
  __shared__ int s_wp[4], s_wn[4];
  __shared__ float s_red[8];
  int tid = threadIdx.x, img = blockIdx.y;
  int r = blockIdx.x*256 + tid;
  size_t o = (size_t)img*R_ANCH + r;
  int lab = label[o];
  bool pos = (lab==1), neg = (lab==0);
  u64 bp = __ballot(pos), bn = __ballot(neg);
  int wid = tid>>6, lane = tid&63;
  if (lane==0){ s_wp[wid]=__popcll(bp); s_wn[wid]=__popcll(bn); }
  __syncthreads();
  int pre_p = opos[img*NCHUNK + blockIdx.x];
  int pre_n = oneg[img*NCHUNK + blockIdx.x];
  for (int w=0; w<wid; ++w){ pre_p += s_wp[w]; pre_n += s_wn[w]; }
  u64 lm = (1ull<<lane) - 1ull;
  pre_p += __popcll(bp & lm);
  pre_n += __popcll(bn & lm);
  int np = quota[img*2], nn = quota[img*2+1];
  bool kp = pos && (pre_p < np);
  bool kn = neg && (pre_n < nn);
  float c_cls = (kp||kn) ? nll_i[o] : 0.0f;
  float c_loc = kp ? loc_i[o] : 0.0f;
  for (int of=32; of>0; of>>=1){
    c_cls += __shfl_down(c_cls, of, 64);
    c_loc += __shfl_down(c_loc, of, 64);
  }
  if (lane==0){ s_red[wid]=c_cls; s_red[4+wid]=c_loc; }
  __syncthreads();
  if (tid==0){
    float a = s_red[0]+s_red[1]+s_red[2]+s_red[3];
    float b = s_red[4]+s_red[5]+s_red[6]+s_red[7];
    if (a != 0.0f) atomicAdd(&acc[0], a);
    if (b != 0.0f) atomicAdd(&acc[1], b);
  }
}

// ---------------- F: stable compaction to 1000 + outputs ------------------
__global__ __launch_bounds__(256) void kF_final(
    const float* __restrict__ tb, const float* __restrict__ tu,
    const float* __restrict__ ts, const u64* __restrict__ keepw,
    const float* __restrict__ acc, float* __restrict__ out) {
  __shared__ int s_wk[4], s_wn[4];
  __shared__ int s_kc, s_runk, s_runn;
  int tid = threadIdx.x, img = blockIdx.x;
  int wid = tid>>6, lane = tid&63;
  const u64* kw = keepw + img*32;
  const float NEG_INF = __uint_as_float(0xff800000u);
  int cnt = 0;
  for (int c=0; c<8; ++c){
    int p = c*256 + tid;
    float4 b = ((const float4*)tb)[(size_t)img*PRE + p];
    bool kp = (p < PRE) && (((kw[p>>6]>>(p&63))&1ull)!=0ull) && (b.z > b.x) && (b.w > b.y);
    cnt += kp ? 1 : 0;
  }
  for (int of=32; of>0; of>>=1) cnt += __shfl_down(cnt, of, 64);
  if (lane==0) s_wk[wid] = cnt;
  __syncthreads();
  if (tid==0){ s_kc = s_wk[0]+s_wk[1]+s_wk[2]+s_wk[3]; s_runk=0; s_runn=0; }
  __syncthreads();
  int kc = s_kc;
  for (int c=0; c<8; ++c){
    int p = c*256 + tid;
    float4 b = ((const float4*)tb)[(size_t)img*PRE + p];
    bool kp = (p < PRE) && (((kw[p>>6]>>(p&63))&1ull)!=0ull) && (b.z > b.x) && (b.w > b.y);
    u64 bk = __ballot(kp), bn = __ballot(!kp);
    if (lane==0){ s_wk[wid]=__popcll(bk); s_wn[wid]=__popcll(bn); }
    __syncthreads();
    int pk = s_runk, pn = s_runn;
    for (int w=0; w<wid; ++w){ pk += s_wk[w]; pn += s_wn[w]; }
    u64 lm = (1ull<<lane) - 1ull;
    pk += __popcll(bk & lm);
    pn += __popcll(bn & lm);
    int slot = kp ? pk : (kc + pn);
    if (slot < POST && p < PRE){
      ((float4*)out)[img*POST + slot] = b;
      out[32000 + img*POST + slot] = kp ? ts[img*PRE + p] : NEG_INF;
      ((float2*)(out + 40000))[img*POST + slot] = ((const float2*)tu)[(size_t)img*PRE + p];
    }
    __syncthreads();
    if (tid==0){
      s_runk += s_wk[0]+s_wk[1]+s_wk[2]+s_wk[3];
      s_runn += s_wn[0]+s_wn[1]+s_wn[2]+s_wn[3];
    }
    __syncthreads();
  }
  if (img==0 && tid<2) out[56000+tid] = acc[tid] * (1.0f/2048.0f);
}

// ---------------- host-side launch ----------------------------------------
extern "C" void kernel_launch(void* const* d_in, const int* in_sizes, int n_in,
                              void* d_out, int out_size, void* d_ws, size_t ws_size,
                              hipStream_t stream) {
  const float* anchors = (const float*)d_in[0];
  const float* pi      = (const float*)d_in[1];
  const float* mu      = (const float*)d_in[2];
  const float* sigma   = (const float*)d_in[3];
  const float* deltas  = (const float*)d_in[4];
  const float* gt      = (const float*)d_in[5];
  float* out = (float*)d_out;

  char* ws = (char*)d_ws;
  size_t off = 0;
  auto alloc = [&](size_t bytes) -> void* {
    void* p = (void*)(ws + off);
    off += (bytes + 255) & ~(size_t)255;
    return p;
  };
  float* logits = (float*)alloc((size_t)NIMG*R_ANCH*4);
  float* epis   = (float*)alloc((size_t)NIMG*R_ANCH*4);
  float* alea   = (float*)alloc((size_t)NIMG*R_ANCH*4);
  float* nll    = (float*)alloc((size_t)NIMG*R_ANCH*4);
  float* loc    = (float*)alloc((size_t)NIMG*R_ANCH*4);
  float* tb     = (float*)alloc((size_t)NIMG*PRE*4*4);
  float* tu     = (float*)alloc((size_t)NIMG*PRE*2*4);
  float* ts     = (float*)alloc((size_t)NIMG*PRE*4);
  u64*   maskLT = (u64*)  alloc((size_t)NIMG*32*MROW*8);
  u16*   slist  = (u16*)  alloc((size_t)NIMG*2048*SCAP*2);
  u64*   keepw  = (u64*)  alloc((size_t)NIMG*32*8);
  u64*   cand   = (u64*)  alloc((size_t)NIMG*4096*8);
  int*   cpos   = (int*)  alloc((size_t)NIMG*NCHUNK*4);
  int*   cneg   = (int*)  alloc((size_t)NIMG*NCHUNK*4);
  int*   opos   = (int*)  alloc((size_t)NIMG*NCHUNK*4);
  int*   oneg   = (int*)  alloc((size_t)NIMG*NCHUNK*4);
  int*   quota  = (int*)  alloc((size_t)NIMG*2*4);
  // ---- contiguous zero region ----
  size_t zstart = off;
  u32*   hist0  = (u32*)  alloc((size_t)NIMG*2048*4);
  u32*   hist1  = (u32*)  alloc((size_t)NIMG*2048*4);
  u32*   hist2  = (u32*)  alloc((size_t)NIMG*2048*4);
  u32*   gcnt   = (u32*)  alloc((size_t)NIMG*GC_STRIDE*4);
  int*   best   = (int*)  alloc((size_t)NIMG*NGT*4);
  u32*   scnt   = (u32*)  alloc((size_t)NIMG*2048*4);
  float* acc    = (float*)alloc(8);
  int zwords = (int)((off - zstart) / 4);
  // label aliases logits: logits last read in kGather; kL2 runs after kE.
  signed char* label = (signed char*)logits;

  kZero<<<dim3(64), dim3(256), 0, stream>>>((u32*)(ws + zstart), zwords);
  kA_mdn<<<dim3(NCHUNK, NIMG), dim3(256), 0, stream>>>(pi, mu, sigma, logits, epis, alea,
                                                       hist0, anchors, gt, deltas, nll, loc);
  kL1_bestgt<<<dim3(NBLK, NIMG), dim3(256), 0, stream>>>(anchors, gt, best);
  kP1<<<dim3(NBLK, NIMG), dim3(256), 0, stream>>>(logits, hist0, hist1);
  kP2<<<dim3(NBLK, NIMG), dim3(256), 0, stream>>>(logits, hist0, hist1, hist2);
  kGather<<<dim3(NBLK, NIMG), dim3(256), 0, stream>>>(logits, hist0, hist1, hist2, cand, gcnt);
  kRank<<<dim3(NIMG), dim3(1024), 0, stream>>>(cand, gcnt, epis, alea, deltas, anchors, tb, tu, ts);
  kD_mask<<<dim3(32, NIMG), dim3(1024), 0, stream>>>(tb, maskLT, scnt, slist);
  kE_nms<<<dim3(NIMG), dim3(1024), 0, stream>>>(maskLT, scnt, slist, keepw);
  kL2_label<<<dim3(NCHUNK, NIMG), dim3(256), 0, stream>>>(anchors, gt, best, label, cpos, cneg);
  kL3_scan<<<dim3(NIMG), dim3(512), 0, stream>>>(cpos, cneg, opos, oneg, quota);
  kL4_accum<<<dim3(NCHUNK, NIMG), dim3(256), 0, stream>>>(label, nll, loc, opos, oneg, quota, acc);
  kF_final<<<dim3(NIMG), dim3(256), 0, stream>>>(tb, tu, ts, keepw, acc, out);
}